// Round 1
// baseline (2742.549 us; speedup 1.0000x reference)
//
#include <hip/hip_runtime.h>

#define HH 384
#define WW 384
#define BB 2

// ---------------------------------------------------------------------------
// Conv 3x3 SAME, NCHW, OIHW weights. Block = 256 threads, 16x16 pixel tile,
// all CO channels. Thread register tile: 8 co x 8 px. ci chunked by 16 via LDS.
// ---------------------------------------------------------------------------
template<int CI, int CO, bool RELU, bool RES>
__global__ __launch_bounds__(256, 2)
void conv3x3_k(const float* __restrict__ in, const float* __restrict__ wgt,
               const float* __restrict__ bias, const float* res, float* out)
{
    constexpr int CHUNK = (CI < 16) ? CI : 16;
    constexpr int COP = 64;                       // padded co (CO=35 padded)
    __shared__ float s_in[CHUNK * 18 * 20];       // stride 20: float4-aligned rows
    __shared__ float s_w[CHUNK * 9 * COP];        // [ci][ky][kx][co]

    const int tid = threadIdx.x;
    const int x0 = blockIdx.x * 16, y0 = blockIdx.y * 16, b = blockIdx.z;
    const int co_grp = tid >> 5;                  // 0..7
    const int pg = tid & 31;                      // 0..31
    const int trow = pg >> 1;                     // 0..15
    const int xoff = (pg & 1) * 8;                // 0 or 8
    const int co_base = co_grp * 8;

    float acc[8][8];
#pragma unroll
    for (int i = 0; i < 8; ++i)
#pragma unroll
        for (int j = 0; j < 8; ++j) acc[i][j] = 0.f;

    for (int c0 = 0; c0 < CI; c0 += CHUNK) {
        __syncthreads();
        // stage input tile (18x18 halo) for this ci chunk
        for (int idx = tid; idx < CHUNK * 18 * 18; idx += 256) {
            int ci = idx / 324, rem = idx - ci * 324;
            int r = rem / 18, c = rem - r * 18;
            int y = y0 - 1 + r, x = x0 - 1 + c;
            float v = 0.f;
            if ((unsigned)y < HH && (unsigned)x < WW)
                v = in[(((size_t)b * CI + c0 + ci) * HH + y) * WW + x];
            s_in[ci * 360 + r * 20 + c] = v;
        }
        // stage weights transposed to [ci][k][co]
        for (int idx = tid; idx < CHUNK * 9 * COP; idx += 256) {
            int co = idx & 63;
            int t = idx >> 6;                     // ci*9 + k
            int ci = t / 9, k = t - ci * 9;
            float v = 0.f;
            if (co < CO) v = wgt[((size_t)co * CI + c0 + ci) * 9 + k];
            s_w[t * COP + co] = v;
        }
        __syncthreads();
#pragma unroll 2
        for (int ci = 0; ci < CHUNK; ++ci) {
#pragma unroll
            for (int ky = 0; ky < 3; ++ky) {
                const float4* rp = reinterpret_cast<const float4*>(
                    &s_in[ci * 360 + (trow + ky) * 20 + xoff]);
                float4 a0 = rp[0], a1 = rp[1], a2 = rp[2];
                float xv[12] = {a0.x, a0.y, a0.z, a0.w, a1.x, a1.y, a1.z, a1.w,
                                a2.x, a2.y, a2.z, a2.w};
#pragma unroll
                for (int kx = 0; kx < 3; ++kx) {
                    const float4* wp = reinterpret_cast<const float4*>(
                        &s_w[(ci * 9 + ky * 3 + kx) * COP + co_base]);
                    float4 w0 = wp[0], w1 = wp[1];
                    float wv[8] = {w0.x, w0.y, w0.z, w0.w, w1.x, w1.y, w1.z, w1.w};
#pragma unroll
                    for (int cc = 0; cc < 8; ++cc)
#pragma unroll
                        for (int p = 0; p < 8; ++p)
                            acc[cc][p] = fmaf(wv[cc], xv[p + kx], acc[cc][p]);
                }
            }
        }
    }
    const int y = y0 + trow;
#pragma unroll
    for (int cc = 0; cc < 8; ++cc) {
        const int co = co_base + cc;
        if (CO < COP && co >= CO) break;          // folded away when CO==64
        const float bv = bias[co];
        size_t obase = (((size_t)b * CO + co) * HH + y) * WW + x0 + xoff;
#pragma unroll
        for (int p = 0; p < 8; ++p) {
            float v = acc[cc][p] + bv;
            if (RES) v += res[obase + p];
            if (RELU) v = fmaxf(v, 0.f);
            out[obase + p] = v;
        }
    }
}

// ---------------------------------------------------------------------------
// KPN aggregation: radial kernel expansion + softmax + patch weighted sum.
// Compile-time radial tables: value depends only on integer d2.
// ---------------------------------------------------------------------------
template<int W>
struct RTabT {
    int lo[(W - 1) * (W - 1) + 1];
    int mult[(W - 1) * (W - 1) + 1];
    int nin;
    constexpr RTabT() : lo{}, mult{}, nin(0) {
        const int R = W - 1, K = 2 * W - 1, R2 = R * R;
        for (int d2 = 0; d2 <= R2; ++d2) {
            int r = 0;
            while ((r + 1) * (r + 1) <= d2) ++r;
            lo[d2] = r;
        }
        for (int i = 0; i < K; ++i)
            for (int j = 0; j < K; ++j) {
                int d2 = (i - R) * (i - R) + (j - R) * (j - R);
                if (d2 <= R2) { mult[d2]++; nin++; }
            }
    }
};
template<int W> __device__ constexpr RTabT<W> rtab{};

template<int W, int OFF>
struct KpnSec {
    static constexpr int R = W - 1, K = 2 * W - 1, R2 = R * R;
    static __device__ __forceinline__ float run(const float (&cv)[35],
                                                const float* s_f, int ty, int tx) {
        float vt[R2 + 1];
        float maxv = 0.f;
#pragma unroll
        for (int d2 = 0; d2 <= R2; ++d2) {
            const int lo = rtab<W>.lo[d2];
            float v;
            if (lo * lo == d2) {
                v = cv[OFF + lo];
            } else {
                const float fr = sqrtf((float)d2) - (float)lo;   // const-folds
                v = fmaf(fr, cv[OFF + lo + 1] - cv[OFF + lo], cv[OFF + lo]);
            }
            vt[d2] = v;
            maxv = fmaxf(maxv, v);
        }
        const float et0 = __expf(-maxv);          // outside-radius entries (val=0)
#pragma unroll
        for (int d2 = 0; d2 <= R2; ++d2) vt[d2] = __expf(vt[d2] - maxv);
        float den = (float)(K * K - rtab<W>.nin) * et0;
#pragma unroll
        for (int d2 = 0; d2 <= R2; ++d2) {
            const int m = rtab<W>.mult[d2];
            if (m > 0) den = fmaf((float)m, vt[d2], den);
        }
        float num = 0.f;
#pragma unroll
        for (int i = 0; i < K; ++i) {
            const int rb = (ty + 7 + i - R) * 48 + (tx + 7 - R);
#pragma unroll
            for (int j = 0; j < K; ++j) {
                const int d2 = (i - R) * (i - R) + (j - R) * (j - R);
                float e;
                if (d2 <= R2) e = vt[d2]; else e = et0;
                num = fmaf(e, s_f[rb + j], num);
            }
        }
        return num / den;
    }
};

__global__ __launch_bounds__(256)
void kpn_k(const float* __restrict__ core, const float* __restrict__ frames,
           float* __restrict__ out)
{
    __shared__ float s_f[30 * 48];                // 16x16 tile + halo 7, stride 48
    const int tid = threadIdx.x;
    const int x0 = blockIdx.x * 16, y0 = blockIdx.y * 16, b = blockIdx.z;
    for (int idx = tid; idx < 900; idx += 256) {
        int r = idx / 30, c = idx - r * 30;
        int y = y0 - 7 + r, x = x0 - 7 + c;
        float v = 0.f;
        if ((unsigned)y < HH && (unsigned)x < WW)
            v = frames[((size_t)b * HH + y) * WW + x];
        s_f[r * 48 + c] = v;
    }
    __syncthreads();
    const int ty = tid >> 4, tx = tid & 15;
    const int y = y0 + ty, x = x0 + tx;
    float cv[35];
#pragma unroll
    for (int ch = 0; ch < 35; ++ch)
        cv[ch] = fabsf(core[(((size_t)b * 35 + ch) * HH + y) * WW + x]);
    float pred = 0.f;
    pred += KpnSec<2, 0>::run(cv, s_f, ty, tx);
    pred += KpnSec<3, 2>::run(cv, s_f, ty, tx);
    pred += KpnSec<4, 5>::run(cv, s_f, ty, tx);
    pred += KpnSec<5, 9>::run(cv, s_f, ty, tx);
    pred += KpnSec<6, 14>::run(cv, s_f, ty, tx);
    pred += KpnSec<7, 20>::run(cv, s_f, ty, tx);
    pred += KpnSec<8, 27>::run(cv, s_f, ty, tx);
    out[((size_t)b * HH + y) * WW + x] = pred;
}

// ---------------------------------------------------------------------------
extern "C" void kernel_launch(void* const* d_in, const int* in_sizes, int n_in,
                              void* d_out, int out_size, void* d_ws, size_t ws_size,
                              hipStream_t stream)
{
    const float* est     = (const float*)d_in[0];
    const float* data    = (const float*)d_in[1];
    const float* w_first = (const float*)d_in[2];
    const float* b_first = (const float*)d_in[3];
    const float* w1a = (const float*)d_in[4];
    const float* b1a = (const float*)d_in[5];
    const float* w1b = (const float*)d_in[6];
    const float* b1b = (const float*)d_in[7];
    const float* w2a = (const float*)d_in[8];
    const float* b2a = (const float*)d_in[9];
    const float* w2b = (const float*)d_in[10];
    const float* b2b = (const float*)d_in[11];
    const float* w3a = (const float*)d_in[12];
    const float* b3a = (const float*)d_in[13];
    const float* w3b = (const float*)d_in[14];
    const float* b3b = (const float*)d_in[15];
    const float* w_out = (const float*)d_in[16];
    const float* b_out = (const float*)d_in[17];

    float* X = (float*)d_ws;                          // (B,64,H,W)
    float* T = X + (size_t)BB * 64 * HH * WW;         // (B,64,H,W) temp / core

    dim3 blk(256), g(WW / 16, HH / 16, BB);
    conv3x3_k<2, 64, false, false><<<g, blk, 0, stream>>>(est, w_first, b_first, nullptr, X);
    conv3x3_k<64, 64, true,  false><<<g, blk, 0, stream>>>(X, w1a, b1a, nullptr, T);
    conv3x3_k<64, 64, false, true ><<<g, blk, 0, stream>>>(T, w1b, b1b, X, X);
    conv3x3_k<64, 64, true,  false><<<g, blk, 0, stream>>>(X, w2a, b2a, nullptr, T);
    conv3x3_k<64, 64, false, true ><<<g, blk, 0, stream>>>(T, w2b, b2b, X, X);
    conv3x3_k<64, 64, true,  false><<<g, blk, 0, stream>>>(X, w3a, b3a, nullptr, T);
    conv3x3_k<64, 64, false, true ><<<g, blk, 0, stream>>>(T, w3b, b3b, X, X);
    conv3x3_k<64, 35, false, false><<<g, blk, 0, stream>>>(X, w_out, b_out, nullptr, T);
    kpn_k<<<g, blk, 0, stream>>>(T, data, (float*)d_out);
}

// Round 2
// 552.395 us; speedup vs baseline: 4.9648x; 4.9648x over previous
//
#include <hip/hip_runtime.h>

#define HH 384
#define WW 384
#define BB 2

typedef unsigned short ushort_t;
typedef short  s16x8 __attribute__((ext_vector_type(8)));
typedef float  f32x4 __attribute__((ext_vector_type(4)));
typedef int    i32x4 __attribute__((ext_vector_type(4)));
typedef int    i32x2 __attribute__((ext_vector_type(2)));

union V16 { i32x4 i4; s16x8 v; ushort_t h[8]; };
union V8  { i32x2 i2; ushort_t h[4]; };

__device__ __forceinline__ ushort_t f2b(float f) {           // RNE fp32->bf16
    unsigned u = __builtin_bit_cast(unsigned, f);
    u += 0x7fffu + ((u >> 16) & 1u);
    return (ushort_t)(u >> 16);
}
__device__ __forceinline__ float b2f(ushort_t h) {
    return __builtin_bit_cast(float, ((unsigned)h) << 16);
}

// ---------------------------------------------------------------------------
// Weight repack into A-fragment order: per conv, layout [t(9)][s(2)][mt][lane][i]
// co = mt*16 + (lane&15); ci = s*32 + (lane>>4)*8 + i.  bf16.
// Main convs j=0..5 (COT=4): 36864 elems each. w_out j=6 (COT=3): 27648.
// w_first (K=18 padded to 32, 1 K-step): [mt(4)][lane][i]: 2048 elems.
// ---------------------------------------------------------------------------
struct WSrc { const float* p[8]; };

__global__ __launch_bounds__(256)
void repack_k(WSrc ws, ushort_t* __restrict__ Wd)
{
    const int idx = blockIdx.x * 256 + threadIdx.x;          // grid = exactly 250880
    float val = 0.f;
    if (idx < 221184) {
        const int j = idx / 36864, rem = idx - j * 36864;
        const int i = rem & 7, lane = (rem >> 3) & 63;
        const int f = rem >> 9;
        const int mt = f & 3, ts = f >> 2;
        const int s = ts & 1, t = ts >> 1;
        const int co = mt * 16 + (lane & 15);
        const int ci = s * 32 + (lane >> 4) * 8 + i;
        val = ws.p[j][((size_t)(co * 64 + ci)) * 9 + t];
    } else if (idx < 248832) {
        const int rem = idx - 221184;
        const int i = rem & 7, lane = (rem >> 3) & 63;
        const int f = rem >> 9;
        const int mt = f % 3, ts = f / 3;
        const int s = ts & 1, t = ts >> 1;
        const int co = mt * 16 + (lane & 15);
        const int ci = s * 32 + (lane >> 4) * 8 + i;
        val = (co < 35) ? ws.p[6][((size_t)(co * 64 + ci)) * 9 + t] : 0.f;
    } else {
        const int rem = idx - 248832;                        // < 2048
        const int i = rem & 7, lane = (rem >> 3) & 63;
        const int mt = rem >> 9;
        const int co = mt * 16 + (lane & 15);
        const int k = (lane >> 4) * 8 + i;
        if (k < 18) {
            const int ch = (k >= 9) ? 1 : 0;
            const int t = k - ch * 9;
            val = ws.p[7][((size_t)(co * 2 + ch)) * 9 + t];
        }
    }
    Wd[idx] = f2b(val);
}

// ---------------------------------------------------------------------------
// Main conv: implicit GEMM via mfma_f32_16x16x32_bf16.
// Input/output NHWC bf16, channel stride 64. Block = 16x16 px tile, 4 waves.
// Wave w: rows 4w..4w+3 (4 N-tiles of 16 px) x COT M-tiles (16 co each).
// LDS: s4[(r*8+oct)*18 + x] holds pixel (r,x) ci-octet oct (16B).
// ---------------------------------------------------------------------------
template<int COT, int CO, bool RELU, bool RES>
__global__ __launch_bounds__(256, 3)
void conv_mfma(const ushort_t* __restrict__ in, const ushort_t* __restrict__ wp,
               const float* __restrict__ bias, const ushort_t* res,
               ushort_t* __restrict__ out)
{
    __shared__ i32x4 s4[18 * 8 * 18];                        // 41472 B
    const int tid = threadIdx.x;
    const int x0 = blockIdx.x * 16, y0 = blockIdx.y * 16, b = blockIdx.z;

    // stage 18x18 halo tile, all 64 ci (bf16, 128 B / pixel)
    for (int idx = tid; idx < 2592; idx += 256) {
        const int oct = idx & 7;
        const int p = idx >> 3;
        const int r = p / 18, x = p - r * 18;
        const int gy = y0 - 1 + r, gx = x0 - 1 + x;
        i32x4 v = 0;
        if ((unsigned)gy < HH && (unsigned)gx < WW)
            v = ((const i32x4*)(in + ((size_t)((b * HH + gy) * WW + gx)) * 64))[oct];
        s4[(r * 8 + oct) * 18 + x] = v;
    }
    __syncthreads();

    const int lane = tid & 63, w4 = (tid >> 6) * 4;
    const int n = lane & 15, g = lane >> 4;

    f32x4 acc[4][COT];
#pragma unroll
    for (int i = 0; i < 4; ++i)
#pragma unroll
        for (int j = 0; j < COT; ++j) acc[i][j] = 0.f;

#pragma unroll
    for (int ky = 0; ky < 3; ++ky)
#pragma unroll
    for (int kx = 0; kx < 3; ++kx)
#pragma unroll
    for (int s = 0; s < 2; ++s) {
        const int tb = (ky * 3 + kx) * 2 + s;
        V16 af[COT];
#pragma unroll
        for (int mt = 0; mt < COT; ++mt)
            af[mt].i4 = *(const i32x4*)(wp + ((size_t)((tb * COT + mt) * 64 + lane)) * 8);
        V16 bf[4];
#pragma unroll
        for (int nt = 0; nt < 4; ++nt)
            bf[nt].i4 = s4[((w4 + nt + ky) * 8 + s * 4 + g) * 18 + (n + kx)];
#pragma unroll
        for (int nt = 0; nt < 4; ++nt)
#pragma unroll
            for (int mt = 0; mt < COT; ++mt)
                acc[nt][mt] = __builtin_amdgcn_mfma_f32_16x16x32_bf16(
                    af[mt].v, bf[nt].v, acc[nt][mt], 0, 0, 0);
    }

    // epilogue: C/D layout col=lane&15 (px), row=(lane>>4)*4+reg (co_local)
#pragma unroll
    for (int nt = 0; nt < 4; ++nt) {
        const int y = y0 + w4 + nt;
        const size_t pix = ((size_t)(b * HH + y) * WW + x0 + n) * 64;
#pragma unroll
        for (int mt = 0; mt < COT; ++mt) {
            const int co0 = mt * 16 + g * 4;
            if (CO == 64) {
                const float4 bv = *(const float4*)(bias + co0);
                float vv[4] = {acc[nt][mt][0] + bv.x, acc[nt][mt][1] + bv.y,
                               acc[nt][mt][2] + bv.z, acc[nt][mt][3] + bv.w};
                if (RES) {
                    V8 rv; rv.i2 = *(const i32x2*)(res + pix + co0);
#pragma unroll
                    for (int r = 0; r < 4; ++r) vv[r] += b2f(rv.h[r]);
                }
                V8 ov;
#pragma unroll
                for (int r = 0; r < 4; ++r) {
                    float o = RELU ? fmaxf(vv[r], 0.f) : vv[r];
                    ov.h[r] = f2b(o);
                }
                *(i32x2*)(out + pix + co0) = ov.i2;
            } else {
#pragma unroll
                for (int r = 0; r < 4; ++r) {
                    const int co = co0 + r;
                    if (co < CO) {
                        float o = acc[nt][mt][r] + bias[co];
                        out[pix + co] = f2b(o);
                    }
                }
            }
        }
    }
}

// ---------------------------------------------------------------------------
// First conv: CI=2 fp32 NCHW input, K = 2*9 = 18 padded to one K-step of 32.
// ---------------------------------------------------------------------------
__global__ __launch_bounds__(256, 3)
void conv_first(const float* __restrict__ in, const ushort_t* __restrict__ wp,
                const float* __restrict__ bias, ushort_t* __restrict__ out)
{
    __shared__ float s_raw[2][18][20];
    const int tid = threadIdx.x;
    const int x0 = blockIdx.x * 16, y0 = blockIdx.y * 16, b = blockIdx.z;
    for (int idx = tid; idx < 648; idx += 256) {
        const int ch = idx / 324, rem = idx - ch * 324;
        const int r = rem / 18, x = rem - r * 18;
        const int gy = y0 - 1 + r, gx = x0 - 1 + x;
        float v = 0.f;
        if ((unsigned)gy < HH && (unsigned)gx < WW)
            v = in[((size_t)((b * 2 + ch) * HH + gy)) * WW + gx];
        s_raw[ch][r][x] = v;
    }
    __syncthreads();

    const int lane = tid & 63, w4 = (tid >> 6) * 4;
    const int n = lane & 15, g = lane >> 4;

    V16 af[4];
#pragma unroll
    for (int mt = 0; mt < 4; ++mt)
        af[mt].i4 = *(const i32x4*)(wp + ((size_t)(mt * 64 + lane)) * 8);

    f32x4 acc[4][4];
#pragma unroll
    for (int i = 0; i < 4; ++i)
#pragma unroll
        for (int j = 0; j < 4; ++j) acc[i][j] = 0.f;

#pragma unroll
    for (int nt = 0; nt < 4; ++nt) {
        const int r = w4 + nt;
        V16 bf;
#pragma unroll
        for (int i = 0; i < 8; ++i) {
            const int k = g * 8 + i;
            float v = 0.f;
            if (k < 18) {
                const int ch = (k >= 9) ? 1 : 0;
                const int t = k - ch * 9;
                const int ky = t / 3, kx = t - ky * 3;
                v = s_raw[ch][r + ky][n + kx];
            }
            bf.h[i] = f2b(v);
        }
#pragma unroll
        for (int mt = 0; mt < 4; ++mt)
            acc[nt][mt] = __builtin_amdgcn_mfma_f32_16x16x32_bf16(
                af[mt].v, bf.v, acc[nt][mt], 0, 0, 0);
    }

#pragma unroll
    for (int nt = 0; nt < 4; ++nt) {
        const int y = y0 + w4 + nt;
        const size_t pix = ((size_t)(b * HH + y) * WW + x0 + n) * 64;
#pragma unroll
        for (int mt = 0; mt < 4; ++mt) {
            const int co0 = mt * 16 + g * 4;
            const float4 bv = *(const float4*)(bias + co0);
            float vv[4] = {acc[nt][mt][0] + bv.x, acc[nt][mt][1] + bv.y,
                           acc[nt][mt][2] + bv.z, acc[nt][mt][3] + bv.w};
            V8 ov;
#pragma unroll
            for (int r = 0; r < 4; ++r) ov.h[r] = f2b(vv[r]);
            *(i32x2*)(out + pix + co0) = ov.i2;
        }
    }
}

// ---------------------------------------------------------------------------
// KPN aggregation (unchanged math; core now bf16 NHWC, channel stride 64).
// ---------------------------------------------------------------------------
template<int W>
struct RTabT {
    int lo[(W - 1) * (W - 1) + 1];
    int mult[(W - 1) * (W - 1) + 1];
    int nin;
    constexpr RTabT() : lo{}, mult{}, nin(0) {
        const int R = W - 1, K = 2 * W - 1, R2 = R * R;
        for (int d2 = 0; d2 <= R2; ++d2) {
            int r = 0;
            while ((r + 1) * (r + 1) <= d2) ++r;
            lo[d2] = r;
        }
        for (int i = 0; i < K; ++i)
            for (int j = 0; j < K; ++j) {
                int d2 = (i - R) * (i - R) + (j - R) * (j - R);
                if (d2 <= R2) { mult[d2]++; nin++; }
            }
    }
};
template<int W> __device__ constexpr RTabT<W> rtab{};

template<int W, int OFF>
struct KpnSec {
    static constexpr int R = W - 1, K = 2 * W - 1, R2 = R * R;
    static __device__ __forceinline__ float run(const float (&cv)[35],
                                                const float* s_f, int ty, int tx) {
        float vt[R2 + 1];
        float maxv = 0.f;
#pragma unroll
        for (int d2 = 0; d2 <= R2; ++d2) {
            const int lo = rtab<W>.lo[d2];
            float v;
            if (lo * lo == d2) {
                v = cv[OFF + lo];
            } else {
                const float fr = sqrtf((float)d2) - (float)lo;
                v = fmaf(fr, cv[OFF + lo + 1] - cv[OFF + lo], cv[OFF + lo]);
            }
            vt[d2] = v;
            maxv = fmaxf(maxv, v);
        }
        const float et0 = __expf(-maxv);
#pragma unroll
        for (int d2 = 0; d2 <= R2; ++d2) vt[d2] = __expf(vt[d2] - maxv);
        float den = (float)(K * K - rtab<W>.nin) * et0;
#pragma unroll
        for (int d2 = 0; d2 <= R2; ++d2) {
            const int m = rtab<W>.mult[d2];
            if (m > 0) den = fmaf((float)m, vt[d2], den);
        }
        float num = 0.f;
#pragma unroll
        for (int i = 0; i < K; ++i) {
            const int rb = (ty + 7 + i - R) * 48 + (tx + 7 - R);
#pragma unroll
            for (int j = 0; j < K; ++j) {
                const int d2 = (i - R) * (i - R) + (j - R) * (j - R);
                float e;
                if (d2 <= R2) e = vt[d2]; else e = et0;
                num = fmaf(e, s_f[rb + j], num);
            }
        }
        return num / den;
    }
};

__global__ __launch_bounds__(256)
void kpn_k(const ushort_t* __restrict__ core, const float* __restrict__ frames,
           float* __restrict__ out)
{
    __shared__ float s_f[30 * 48];
    const int tid = threadIdx.x;
    const int x0 = blockIdx.x * 16, y0 = blockIdx.y * 16, b = blockIdx.z;
    for (int idx = tid; idx < 900; idx += 256) {
        int r = idx / 30, c = idx - r * 30;
        int y = y0 - 7 + r, x = x0 - 7 + c;
        float v = 0.f;
        if ((unsigned)y < HH && (unsigned)x < WW)
            v = frames[((size_t)b * HH + y) * WW + x];
        s_f[r * 48 + c] = v;
    }
    __syncthreads();
    const int ty = tid >> 4, tx = tid & 15;
    const int y = y0 + ty, x = x0 + tx;
    const size_t pixb = ((size_t)(b * HH + y) * WW + x) * 64;
    float cv[35];
#pragma unroll
    for (int ch = 0; ch < 35; ++ch)
        cv[ch] = fabsf(b2f(core[pixb + ch]));
    float pred = 0.f;
    pred += KpnSec<2, 0>::run(cv, s_f, ty, tx);
    pred += KpnSec<3, 2>::run(cv, s_f, ty, tx);
    pred += KpnSec<4, 5>::run(cv, s_f, ty, tx);
    pred += KpnSec<5, 9>::run(cv, s_f, ty, tx);
    pred += KpnSec<6, 14>::run(cv, s_f, ty, tx);
    pred += KpnSec<7, 20>::run(cv, s_f, ty, tx);
    pred += KpnSec<8, 27>::run(cv, s_f, ty, tx);
    out[((size_t)b * HH + y) * WW + x] = pred;
}

// ---------------------------------------------------------------------------
extern "C" void kernel_launch(void* const* d_in, const int* in_sizes, int n_in,
                              void* d_out, int out_size, void* d_ws, size_t ws_size,
                              hipStream_t stream)
{
    const float* est     = (const float*)d_in[0];
    const float* data    = (const float*)d_in[1];
    const float* w_first = (const float*)d_in[2];
    const float* b_first = (const float*)d_in[3];
    const float* w1a = (const float*)d_in[4];
    const float* b1a = (const float*)d_in[5];
    const float* w1b = (const float*)d_in[6];
    const float* b1b = (const float*)d_in[7];
    const float* w2a = (const float*)d_in[8];
    const float* b2a = (const float*)d_in[9];
    const float* w2b = (const float*)d_in[10];
    const float* b2b = (const float*)d_in[11];
    const float* w3a = (const float*)d_in[12];
    const float* b3a = (const float*)d_in[13];
    const float* w3b = (const float*)d_in[14];
    const float* b3b = (const float*)d_in[15];
    const float* w_out = (const float*)d_in[16];
    const float* b_out = (const float*)d_in[17];

    ushort_t* X  = (ushort_t*)d_ws;                         // NHWC bf16 (B,H,W,64)
    ushort_t* T  = X + (size_t)BB * HH * WW * 64;           // NHWC bf16 (B,H,W,64)
    ushort_t* Wd = T + (size_t)BB * HH * WW * 64;           // repacked weights (250880)

    WSrc wsrc;
    wsrc.p[0] = w1a; wsrc.p[1] = w1b; wsrc.p[2] = w2a; wsrc.p[3] = w2b;
    wsrc.p[4] = w3a; wsrc.p[5] = w3b; wsrc.p[6] = w_out; wsrc.p[7] = w_first;

    dim3 blk(256), g(WW / 16, HH / 16, BB);
    repack_k<<<980, 256, 0, stream>>>(wsrc, Wd);
    conv_first<<<g, blk, 0, stream>>>(est, Wd + 248832, b_first, X);
    conv_mfma<4, 64, true,  false><<<g, blk, 0, stream>>>(X, Wd + 0,      b1a, nullptr, T);
    conv_mfma<4, 64, false, true ><<<g, blk, 0, stream>>>(T, Wd + 36864,  b1b, X, X);
    conv_mfma<4, 64, true,  false><<<g, blk, 0, stream>>>(X, Wd + 73728,  b2a, nullptr, T);
    conv_mfma<4, 64, false, true ><<<g, blk, 0, stream>>>(T, Wd + 110592, b2b, X, X);
    conv_mfma<4, 64, true,  false><<<g, blk, 0, stream>>>(X, Wd + 147456, b3a, nullptr, T);
    conv_mfma<4, 64, false, true ><<<g, blk, 0, stream>>>(T, Wd + 184320, b3b, X, X);
    conv_mfma<3, 35, false, false><<<g, blk, 0, stream>>>(X, Wd + 221184, b_out, nullptr, T);
    kpn_k<<<g, blk, 0, stream>>>(T, data, (float*)d_out);
}